// Round 10
// baseline (32.709 us; speedup 1.0000x reference)
//
#include <hip/hip_runtime.h>

constexpr int CODE_LEN = 1024;
constexpr int INFO_LEN = 512;
constexpr int BATCH    = 2048;
constexpr int ITERS    = 5;
#define CLIPV 15.0f

// f(a,b) = sign(a)*sign(b)*min(|a|,|b|) -- forced 3-inst codegen.
__device__ __forceinline__ float fop(float a, float b) {
    unsigned x; float m, r;
    asm("v_xor_b32 %0, %1, %2" : "=v"(x) : "v"(a), "v"(b));
    asm("v_min_f32 %0, |%1|, |%2|" : "=v"(m) : "v"(a), "v"(b));
    asm("v_and_or_b32 %0, %1, %2, %3" : "=v"(r) : "v"(x), "s"(0x80000000u), "v"(m));
    return r;
}
__device__ __forceinline__ float clipf(float x) {
    return __builtin_amdgcn_fmed3f(x, -CLIPV, CLIPV);
}

// ---------------------------------------------------------------------------
// R7-R9 scheme: position p at (wave,lane,slot) per group; butterflies between
// register slots; conversions move the one boundary array via LDS.
// R10: (a) per-beta rotation layouts word=4*pi_b(g)+s so conversion reads are
// base+{0,64,128,192} dwords (-> 2x ds_read2_b32, 2-lane/bank free);
// (b) CONV_X layout 4*l6+256*w+(s^m), m=(l6>>3)&3: read banks 8-way -> 2-way,
// reads base+{0,256,512,768} (-> ds_read2st64_b32); write-side tuple permute
// by m (8 cndmask); (c) raw s_barrier + lgkmcnt(0) only (no vmcnt drain of
// the emit stores). XB0/XB1 alternation keeps WAR barrier-separated.
// ---------------------------------------------------------------------------

#define RSTEP0(A, B) do { \
    float bu0=(B)[0], bl0=(B)[1], bu1=(B)[2], bl1=(B)[3]; \
    (B)[0]=fop((A)[0], bl0+(A)[1]); \
    (B)[1]=clipf(fop((A)[0], bu0)+(A)[1]); \
    (B)[2]=fop((A)[2], bl1+(A)[3]); \
    (B)[3]=clipf(fop((A)[2], bu1)+(A)[3]); } while(0)
#define RSTEP1(A, B) do { \
    float bu0=(B)[0], bl0=(B)[2], bu1=(B)[1], bl1=(B)[3]; \
    (B)[0]=fop((A)[0], bl0+(A)[2]); \
    (B)[2]=clipf(fop((A)[0], bu0)+(A)[2]); \
    (B)[1]=fop((A)[1], bl1+(A)[3]); \
    (B)[3]=clipf(fop((A)[1], bu1)+(A)[3]); } while(0)
#define LSTEP0(A, B) do { \
    float au0=(A)[0], al0=(A)[1], au1=(A)[2], al1=(A)[3]; \
    (A)[0]=fop((B)[0], (B)[1]+al0); \
    (A)[1]=clipf(fop(au0, (B)[0])+(B)[1]); \
    (A)[2]=fop((B)[2], (B)[3]+al1); \
    (A)[3]=clipf(fop(au1, (B)[2])+(B)[3]); } while(0)
#define LSTEP1(A, B) do { \
    float au0=(A)[0], al0=(A)[2], au1=(A)[1], al1=(A)[3]; \
    (A)[0]=fop((B)[0], (B)[2]+al0); \
    (A)[2]=clipf(fop(au0, (B)[0])+(B)[2]); \
    (A)[1]=fop((B)[1], (B)[3]+al1); \
    (A)[3]=clipf(fop(au1, (B)[1])+(B)[3]); } while(0)
// stage-9 left step: B = rx (UNclipped) -> keep u-clip
#define LSTEP1C(A, B) do { \
    float au0=(A)[0], al0=(A)[2], au1=(A)[1], al1=(A)[3]; \
    (A)[0]=clipf(fop((B)[0], (B)[2]+al0)); \
    (A)[2]=clipf(fop(au0, (B)[0])+(B)[2]); \
    (A)[1]=clipf(fop((B)[1], (B)[3]+al1)); \
    (A)[3]=clipf(fop(au1, (B)[1])+(B)[3]); } while(0)
// iteration-0 right steps (l == 0): u' = fop(r_u, r_l), l' = r_l
#define RSTEP0Z(A, B) do { \
    (B)[0]=fop((A)[0], (A)[1]); (B)[1]=(A)[1]; \
    (B)[2]=fop((A)[2], (A)[3]); (B)[3]=(A)[3]; } while(0)
#define RSTEP1Z(A, B) do { \
    (B)[0]=fop((A)[0], (A)[2]); (B)[2]=(A)[2]; \
    (B)[1]=fop((A)[1], (A)[3]); (B)[3]=(A)[3]; } while(0)

// LDS-only barrier: no vmcnt drain (emit stores stay in flight).
#define XBAR() do { \
    asm volatile("s_waitcnt lgkmcnt(0)" ::: "memory"); \
    __builtin_amdgcn_s_barrier(); \
    __builtin_amdgcn_sched_barrier(0); } while(0)

// in-wave conversion: write b128 at 4*pi(l6), read base+{0,64,128,192} dwords
#define CONV_W(arr, WBASE, RBASE) do { \
    *(float4*)&WB[WBASE] = make_float4((arr)[0], (arr)[1], (arr)[2], (arr)[3]); \
    const float* rp_ = &WB[RBASE]; \
    float c0_ = rp_[0], c1_ = rp_[64], c2_ = rp_[128], c3_ = rp_[192]; \
    (arr)[0]=c0_; (arr)[1]=c1_; (arr)[2]=c2_; (arr)[3]=c3_; } while(0)

// cross-wave conversion: tuple-permute by m, write b128, barrier, strided read
#define CONV_X(arr, XBUF) do { \
    float T0_ = mb0 ? (arr)[1] : (arr)[0]; \
    float T1_ = mb0 ? (arr)[0] : (arr)[1]; \
    float T2_ = mb0 ? (arr)[3] : (arr)[2]; \
    float T3_ = mb0 ? (arr)[2] : (arr)[3]; \
    float U0_ = mb1 ? T2_ : T0_; \
    float U1_ = mb1 ? T3_ : T1_; \
    float U2_ = mb1 ? T0_ : T2_; \
    float U3_ = mb1 ? T1_ : T3_; \
    *(float4*)&(XBUF)[wX] = make_float4(U0_, U1_, U2_, U3_); \
    XBAR(); \
    const float* xp_ = &(XBUF)[rX]; \
    float c0_ = xp_[0], c1_ = xp_[256], c2_ = xp_[512], c3_ = xp_[768]; \
    (arr)[0]=c0_; (arr)[1]=c1_; (arr)[2]=c2_; (arr)[3]=c3_; } while(0)

__global__ __launch_bounds__(256, 4) void polar_bp_r10(const float* __restrict__ rx,
                                                       const int* __restrict__ info,
                                                       float* __restrict__ out) {
    __shared__ int   RK[CODE_LEN];    // rank table in L0 flat order (init only)
    __shared__ float WB[CODE_LEN];    // per-wave conversion scratch (4x256)
    __shared__ float XB0[CODE_LEN];   // cross-wave buffers (alternating)
    __shared__ float XB1[CODE_LEN];

    const int t = threadIdx.x;
    const int b = blockIdx.x;

    // RK[L0-flat] = rank or -1. flat(p) = p10 | p76<<2 | p54<<4 | p32<<6 | p98<<8
    *(int4*)&RK[t * 4] = make_int4(-1, -1, -1, -1);
    __syncthreads();
#pragma unroll
    for (int k = 0; k < 2; ++k) {
        int kk = t + 256 * k;
        int p  = info[kk];
        int fl = (p & 3) | (((p >> 6) & 3) << 2) | (((p >> 4) & 3) << 4)
               | (((p >> 2) & 3) << 6) | (((p >> 8) & 3) << 8);
        RK[fl] = kk;
    }
    __syncthreads();

    // ---- precomputed conversion bases (dword indices, iteration-invariant) ----
    const int l6 = t & 63;
    const int w  = t >> 6;
    const int wbase = w * 256;
    // beta=4: pi = identity
    const int wW4 = wbase + 4 * l6;
    const int rW4 = wbase + 4 * (l6 & 15) + ((l6 >> 4) & 3);
    // beta=2: pi(g) = (g&3) | ((g>>4)&3)<<2 | ((g>>2)&3)<<4
    const int wW2 = wbase + 4 * ((l6 & 3) | (((l6 >> 4) & 3) << 2) | (((l6 >> 2) & 3) << 4));
    const int rW2 = wbase + 4 * ((l6 & 3) | (((l6 >> 4) & 3) << 2)) + ((l6 >> 2) & 3);
    // beta=0: pi(g) = ((g>>2)&15) | (g&3)<<4
    const int wW0 = wbase + 4 * (((l6 >> 2) & 15) | ((l6 & 3) << 4));
    const int rW0 = wbase + 4 * ((l6 >> 2) & 15) + (l6 & 3);
    // CONV_X: word(w',l6',s') = 4*l6' + 256*w' + (s' ^ ((l6'>>3)&3))
    const int  mX  = (l6 >> 3) & 3;
    const bool mb0 = (l6 & 8)  != 0;
    const bool mb1 = (l6 & 16) != 0;
    const int  wX  = 4 * l6 + 256 * w;
    const int  rX  = 4 * l6 + (w ^ mX);

    // ---- per-thread constants: ranks + frozen vector ----
    const int4 rkv = *(const int4*)&RK[t * 4];
    float fr[4];
    fr[0] = rkv.x < 0 ? CLIPV : 0.f;  fr[1] = rkv.y < 0 ? CLIPV : 0.f;
    fr[2] = rkv.z < 0 ? CLIPV : 0.f;  fr[3] = rkv.w < 0 ? CLIPV : 0.f;

    float S[10][4];
    // rx -> S[9] in L4 order: p = e*256 + t76*64 + t10*16 + t32*4 + t54
    {
        const float* rxb = rx + (size_t)b * CODE_LEN
                         + ((t >> 6) & 3) * 64 + (t & 3) * 16
                         + ((t >> 2) & 3) * 4 + ((t >> 4) & 3);
        S[9][0] = rxb[0];   S[9][1] = rxb[256];
        S[9][2] = rxb[512]; S[9][3] = rxb[768];
    }

    // ===== iteration-0 RIGHT pass, peeled: all left arrays are zero =====
    RSTEP0Z(fr, S[0]);
    RSTEP1Z(S[0], S[1]);
    CONV_W(S[1], wW4, rW4);    // C01  L0->L1
    RSTEP0Z(S[1], S[2]);
    RSTEP1Z(S[2], S[3]);
    CONV_W(S[3], wW2, rW2);    // C12  L1->L2
    RSTEP0Z(S[3], S[4]);
    RSTEP1Z(S[4], S[5]);
    CONV_W(S[5], wW0, rW0);    // C23  L2->L3
    RSTEP0Z(S[5], S[6]);
    RSTEP1Z(S[6], S[7]);
    CONV_X(S[7], XB0);         // C34  L3->L4 (barrier)
    RSTEP0Z(S[7], S[8]);       // s8 (right stage 9 output unused)

    float v0, v1, v2, v3;
    float* ob = out + (size_t)b * INFO_LEN;
    const size_t obstride = (size_t)BATCH * INFO_LEN;

#pragma unroll 1
    for (int it = 0; it < ITERS; ++it) {
        // ===================== LEFT pass (s = 9..0) ======================
        LSTEP1C(S[8], S[9]);       // s9: l = rx (unclipped) -> keep u-clip
        LSTEP0(S[7], S[8]);        // s8
        CONV_X(S[7], XB1);         // C43  L4->L3 (barrier)
        LSTEP1(S[6], S[7]);        // s7
        LSTEP0(S[5], S[6]);        // s6
        CONV_W(S[5], wW0, rW0);    // C32  L3->L2
        LSTEP1(S[4], S[5]);        // s5
        LSTEP0(S[3], S[4]);        // s4
        CONV_W(S[3], wW2, rW2);    // C21  L2->L1
        LSTEP1(S[2], S[3]);        // s3
        LSTEP0(S[1], S[2]);        // s2
        CONV_W(S[1], wW4, rW4);    // C10  L1->L0
        LSTEP1(S[0], S[1]);        // s1 -> S[0] = left[1]
        // s0: emit left[0] at info positions (right[0] = 0 there), L0 order
        v0 = fop(S[0][0], S[0][1] + fr[1]);
        v1 = clipf(fop(fr[0], S[0][0]) + S[0][1]);
        v2 = fop(S[0][2], S[0][3] + fr[3]);
        v3 = clipf(fop(fr[2], S[0][2]) + S[0][3]);
        if (rkv.x >= 0) ob[rkv.x] = v0;
        if (rkv.y >= 0) ob[rkv.y] = v1;
        if (rkv.z >= 0) ob[rkv.z] = v2;
        if (rkv.w >= 0) ob[rkv.w] = v3;
        ob += obstride;
        // ===================== RIGHT pass (s = 0..8) =====================
        if (it != ITERS - 1) {
            RSTEP0(fr, S[0]);
            RSTEP1(S[0], S[1]);
            CONV_W(S[1], wW4, rW4);    // C01
            RSTEP0(S[1], S[2]);
            RSTEP1(S[2], S[3]);
            CONV_W(S[3], wW2, rW2);    // C12
            RSTEP0(S[3], S[4]);
            RSTEP1(S[4], S[5]);
            CONV_W(S[5], wW0, rW0);    // C23
            RSTEP0(S[5], S[6]);
            RSTEP1(S[6], S[7]);
            CONV_X(S[7], XB0);         // C34 (barrier)
            RSTEP0(S[7], S[8]);
        }
    }
    // duplicate row: out[ITERS] = out[ITERS-1]
    if (rkv.x >= 0) ob[rkv.x] = v0;
    if (rkv.y >= 0) ob[rkv.y] = v1;
    if (rkv.z >= 0) ob[rkv.z] = v2;
    if (rkv.w >= 0) ob[rkv.w] = v3;
}

extern "C" void kernel_launch(void* const* d_in, const int* in_sizes, int n_in,
                              void* d_out, int out_size, void* d_ws, size_t ws_size,
                              hipStream_t stream) {
    const float* rx   = (const float*)d_in[0];
    const int*   info = (const int*)d_in[1];
    float*       outp = (float*)d_out;
    polar_bp_r10<<<dim3(BATCH), dim3(256), 0, stream>>>(rx, info, outp);
}